// Round 3
// baseline (2813.602 us; speedup 1.0000x reference)
//
#include <hip/hip_runtime.h>
#include <hip/hip_bf16.h>
#include <cstdint>
#include <cstddef>

typedef __attribute__((ext_vector_type(8))) short short8;
typedef __attribute__((ext_vector_type(4))) float floatx4;
typedef __attribute__((ext_vector_type(4))) unsigned short ushort4e;

#define B_   4
#define S_   2048
#define D_   1024
#define H_   16
#define DK_  64
#define DFF_ 4096
#define MTOT (B_ * S_)   // 8192

__device__ __forceinline__ float bf2f(unsigned short u) {
    union { unsigned int i; float f; } v; v.i = ((unsigned int)u) << 16; return v.f;
}
__device__ __forceinline__ unsigned short f2bf(float f) {
    union { float f; unsigned int i; } v; v.f = f;
    unsigned int u = v.i;
    u += 0x7fffu + ((u >> 16) & 1u);   // RNE
    return (unsigned short)(u >> 16);
}

// ------------------------------------------------------- dtype detection --
// Reads the first 4096 shorts of x as bf16. If x is really fp32, half of
// these words are random mantissa bits -> values >> 50 (or NaN) appear with
// near-certainty. bf16 N(0,1) data stays < ~7.
__global__ void dtype_probe(const unsigned short* __restrict__ x, int* flag) {
    __shared__ float red[4];
    const int tid = threadIdx.x;
    float mx = 0.f;
    #pragma unroll
    for (int i = 0; i < 16; i++) {
        float v = fabsf(bf2f(x[tid * 16 + i]));
        if (v != v) v = 1e30f;           // NaN -> huge
        mx = fmaxf(mx, v);
    }
    #pragma unroll
    for (int off = 32; off > 0; off >>= 1) mx = fmaxf(mx, __shfl_down(mx, off));
    if ((tid & 63) == 0) red[tid >> 6] = mx;
    __syncthreads();
    if (tid == 0) {
        float m = fmaxf(fmaxf(red[0], red[1]), fmaxf(red[2], red[3]));
        *flag = (m > 50.f) ? 1 : 0;
    }
}

// Convert (or copy) a float tensor into bf16. n8 = elem_count / 8.
__global__ void cvt_kernel(const void* __restrict__ src,
                           unsigned short* __restrict__ dst,
                           int n8, const int* __restrict__ flag) {
    const int i = blockIdx.x * 256 + threadIdx.x;
    if (i >= n8) return;
    if (*flag) {
        const floatx4* s = (const floatx4*)src;
        floatx4 a = s[i * 2], b = s[i * 2 + 1];
        short8 o;
        o[0] = (short)f2bf(a[0]); o[1] = (short)f2bf(a[1]);
        o[2] = (short)f2bf(a[2]); o[3] = (short)f2bf(a[3]);
        o[4] = (short)f2bf(b[0]); o[5] = (short)f2bf(b[1]);
        o[6] = (short)f2bf(b[2]); o[7] = (short)f2bf(b[3]);
        ((short8*)dst)[i] = o;
    } else {
        ((short8*)dst)[i] = ((const short8*)src)[i];
    }
}

// ---------------------------------------------------------------- GEMM ----
// C[M,N] = A[M,K](lda) @ W[N,K](ldw)^T (+bias)(+residual)(ReLU?) ; A,W bf16
#define BM 128
#define BN 128
#define BK 64
#define LDK (BK + 8)   // 72 elems

template<int RELU, int HAS_BIAS, int RES_MODE, int OUT_F32>
__global__ __launch_bounds__(256)
void gemm_bt(const unsigned short* __restrict__ A, int lda,
             const unsigned short* __restrict__ W, int ldw,
             const unsigned short* __restrict__ bias,
             const void* resid,
             void* out,
             int M, int N, int K)
{
    __shared__ unsigned short As[BM * LDK];
    __shared__ unsigned short Bs[BN * LDK];

    const int tid  = threadIdx.x;
    const int lane = tid & 63;
    const int wave = tid >> 6;
    const int wm = wave >> 1;
    const int wn = wave & 1;
    const int lr = lane & 15;
    const int lq = lane >> 4;

    const int m0 = blockIdx.y * BM;
    const int n0 = blockIdx.x * BN;

    floatx4 acc[4][4];
    #pragma unroll
    for (int i = 0; i < 4; i++)
        #pragma unroll
        for (int j = 0; j < 4; j++)
            acc[i][j] = (floatx4){0.f, 0.f, 0.f, 0.f};

    const int sr = tid >> 3;
    const int sc = (tid & 7) * 8;

    for (int k0 = 0; k0 < K; k0 += BK) {
        #pragma unroll
        for (int p = 0; p < 4; p++) {
            const int row = sr + p * 32;
            short8 av = *(const short8*)(A + (size_t)(m0 + row) * lda + k0 + sc);
            short8 bv = *(const short8*)(W + (size_t)(n0 + row) * ldw + k0 + sc);
            *(short8*)(&As[row * LDK + sc]) = av;
            *(short8*)(&Bs[row * LDK + sc]) = bv;
        }
        __syncthreads();
        #pragma unroll
        for (int kk = 0; kk < BK; kk += 32) {
            short8 af[4], bfr[4];
            #pragma unroll
            for (int i = 0; i < 4; i++) {
                af[i]  = *(const short8*)(&As[(wm * 64 + i * 16 + lr) * LDK + kk + lq * 8]);
                bfr[i] = *(const short8*)(&Bs[(wn * 64 + i * 16 + lr) * LDK + kk + lq * 8]);
            }
            #pragma unroll
            for (int i = 0; i < 4; i++)
                #pragma unroll
                for (int j = 0; j < 4; j++)
                    acc[i][j] = __builtin_amdgcn_mfma_f32_16x16x32_bf16(
                                    af[i], bfr[j], acc[i][j], 0, 0, 0);
        }
        __syncthreads();
    }

    #pragma unroll
    for (int i = 0; i < 4; i++) {
        #pragma unroll
        for (int j = 0; j < 4; j++) {
            const int col = n0 + wn * 64 + j * 16 + lr;
            const float bv = HAS_BIAS ? bf2f(bias[col]) : 0.f;
            #pragma unroll
            for (int r = 0; r < 4; r++) {
                const int row = m0 + wm * 64 + i * 16 + lq * 4 + r;
                float vvv = acc[i][j][r] + bv;
                if (RES_MODE == 1) vvv += bf2f(((const unsigned short*)resid)[(size_t)row * N + col]);
                if (RES_MODE == 2) vvv += ((const float*)resid)[(size_t)row * N + col];
                if (RELU) vvv = fmaxf(vvv, 0.f);
                if (OUT_F32) ((float*)out)[(size_t)row * N + col] = vvv;
                else ((unsigned short*)out)[(size_t)row * N + col] = f2bf(vvv);
            }
        }
    }
}

// ------------------------------------------------------------- LayerNorm --
template<int IN_F32>
__global__ __launch_bounds__(256)
void ln_kernel(const void* __restrict__ Xv,
               const unsigned short* __restrict__ g,
               const unsigned short* __restrict__ be,
               unsigned short* __restrict__ out)
{
    const int row = blockIdx.x;
    const int tid = threadIdx.x;
    float x4[4];
    if (IN_F32) {
        const float* X = (const float*)Xv + (size_t)row * D_ + tid * 4;
        floatx4 t = *(const floatx4*)X;
        x4[0] = t[0]; x4[1] = t[1]; x4[2] = t[2]; x4[3] = t[3];
    } else {
        const unsigned short* X = (const unsigned short*)Xv + (size_t)row * D_ + tid * 4;
        ushort4e u = *(const ushort4e*)X;
        #pragma unroll
        for (int i = 0; i < 4; i++) x4[i] = bf2f(u[i]);
    }
    float s1 = x4[0] + x4[1] + x4[2] + x4[3];
    float s2 = x4[0]*x4[0] + x4[1]*x4[1] + x4[2]*x4[2] + x4[3]*x4[3];
    #pragma unroll
    for (int off = 32; off > 0; off >>= 1) {
        s1 += __shfl_down(s1, off);
        s2 += __shfl_down(s2, off);
    }
    __shared__ float r1[4], r2[4];
    const int wv = tid >> 6;
    if ((tid & 63) == 0) { r1[wv] = s1; r2[wv] = s2; }
    __syncthreads();
    s1 = r1[0] + r1[1] + r1[2] + r1[3];
    s2 = r2[0] + r2[1] + r2[2] + r2[3];
    const float mean = s1 * (1.0f / D_);
    const float var  = (s2 - (float)D_ * mean * mean) * (1.0f / (D_ - 1));
    const float rstd = rsqrtf(var + 1e-9f);

    ushort4e o4;
    #pragma unroll
    for (int i = 0; i < 4; i++) {
        const float gv = bf2f(g[tid * 4 + i]);
        const float bv = bf2f(be[tid * 4 + i]);
        o4[i] = f2bf(gv * (x4[i] - mean) * rstd + bv);
    }
    *(ushort4e*)(out + (size_t)row * D_ + tid * 4) = o4;
}

// ------------------------------------------------------------- Attention --
#define TK  64
#define LDA (DK_ + 4)

__global__ __launch_bounds__(128)
void attn_kernel(const unsigned short* __restrict__ Q,
                 const unsigned short* __restrict__ Kg,
                 const unsigned short* __restrict__ Vg,
                 const int* __restrict__ mask,
                 unsigned short* __restrict__ ctx)
{
    __shared__ float Kt[TK * LDA];
    __shared__ float Vt[TK * LDA];
    __shared__ float mb[TK];

    const int tid  = threadIdx.x;
    const int bh   = blockIdx.y;
    const int b    = bh >> 4;
    const int h    = bh & 15;
    const int qrow = blockIdx.x * 128 + tid;

    float q[DK_];
    {
        const unsigned short* qp = Q + (size_t)(b * S_ + qrow) * D_ + h * DK_;
        #pragma unroll
        for (int i = 0; i < DK_ / 8; i++) {
            short8 v = *(const short8*)(qp + i * 8);
            #pragma unroll
            for (int e = 0; e < 8; e++) q[i * 8 + e] = bf2f((unsigned short)v[e]) * 0.125f;
        }
    }
    float o[DK_];
    #pragma unroll
    for (int d = 0; d < DK_; d++) o[d] = 0.f;
    float mrun = -1.0e30f, lrun = 0.f;

    const int srow = tid >> 1;
    const int scol = (tid & 1) * 32;

    #pragma unroll 1
    for (int kt = 0; kt < S_; kt += TK) {
        {
            const unsigned short* kp = Kg + (size_t)(b * S_ + kt + srow) * D_ + h * DK_ + scol;
            const unsigned short* vp = Vg + (size_t)(b * S_ + kt + srow) * D_ + h * DK_ + scol;
            #pragma unroll
            for (int i = 0; i < 4; i++) {
                short8 kv = *(const short8*)(kp + i * 8);
                short8 vv = *(const short8*)(vp + i * 8);
                #pragma unroll
                for (int e = 0; e < 8; e++) {
                    Kt[srow * LDA + scol + i * 8 + e] = bf2f((unsigned short)kv[e]);
                    Vt[srow * LDA + scol + i * 8 + e] = bf2f((unsigned short)vv[e]);
                }
            }
            if (tid < TK) mb[tid] = (mask[b * S_ + kt + tid] == 0) ? 1.f : 0.f;
        }
        __syncthreads();
        #pragma unroll 1
        for (int j = 0; j < TK; j++) {
            const float* kr = &Kt[j * LDA];
            float sa0 = 0.f, sa1 = 0.f, sa2 = 0.f, sa3 = 0.f;
            #pragma unroll
            for (int d = 0; d < DK_; d += 16) {
                floatx4 k0 = *(const floatx4*)(kr + d);
                floatx4 k1 = *(const floatx4*)(kr + d + 4);
                floatx4 k2 = *(const floatx4*)(kr + d + 8);
                floatx4 k3 = *(const floatx4*)(kr + d + 12);
                sa0 += q[d+0]*k0[0] + q[d+1]*k0[1] + q[d+2]*k0[2] + q[d+3]*k0[3];
                sa1 += q[d+4]*k1[0] + q[d+5]*k1[1] + q[d+6]*k1[2] + q[d+7]*k1[3];
                sa2 += q[d+8]*k2[0] + q[d+9]*k2[1] + q[d+10]*k2[2] + q[d+11]*k2[3];
                sa3 += q[d+12]*k3[0] + q[d+13]*k3[1] + q[d+14]*k3[2] + q[d+15]*k3[3];
            }
            float s = (sa0 + sa1) + (sa2 + sa3);
            if (mb[j] != 0.f) s = -1e9f;
            const float* vr = &Vt[j * LDA];
            const float mnew  = fmaxf(mrun, s);
            const float alpha = __expf(mrun - mnew);
            const float p     = __expf(s - mnew);
            lrun = lrun * alpha + p;
            #pragma unroll
            for (int d = 0; d < DK_; d++) o[d] = o[d] * alpha + p * vr[d];
            mrun = mnew;
        }
        __syncthreads();
    }

    const float inv = 1.0f / lrun;
    unsigned short* cp = ctx + (size_t)(b * S_ + qrow) * D_ + h * DK_;
    #pragma unroll
    for (int i = 0; i < DK_ / 8; i++) {
        short8 ov;
        #pragma unroll
        for (int e = 0; e < 8; e++) ov[e] = (short)f2bf(o[i * 8 + e] * inv);
        *(short8*)(cp + i * 8) = ov;
    }
}

// --------------------------------------------------------------- epilogue --
// out = h1 + b2, stored per runtime flag (fp32 or bf16)
__global__ __launch_bounds__(256)
void epi_kernel(const float* __restrict__ h1,
                const unsigned short* __restrict__ b2,
                void* out, const int* __restrict__ flag)
{
    const int row = blockIdx.x, tid = threadIdx.x;
    floatx4 h = *(const floatx4*)(h1 + (size_t)row * D_ + tid * 4);
    ushort4e bb = *(const ushort4e*)(b2 + tid * 4);
    float r0 = h[0] + bf2f(bb[0]);
    float r1 = h[1] + bf2f(bb[1]);
    float r2 = h[2] + bf2f(bb[2]);
    float r3 = h[3] + bf2f(bb[3]);
    if (*flag) {
        floatx4 o = (floatx4){r0, r1, r2, r3};
        *(floatx4*)((float*)out + (size_t)row * D_ + tid * 4) = o;
    } else {
        ushort4e o;
        o[0] = f2bf(r0); o[1] = f2bf(r1); o[2] = f2bf(r2); o[3] = f2bf(r3);
        *(ushort4e*)((unsigned short*)out + (size_t)row * D_ + tid * 4) = o;
    }
}

// ---------------------------------------------------------------- launch --
// ws layout (bytes):
//   [0,4):       flag
//   [1K,64K):    converted small tensors (b1@1K, b2@16K, g1@32K, be1@40K, g2@48K, be2@56K)
//   [1M,3M):     cwq   [3M,5M): cwk   [5M,7M): cwv   [7M,9M): cwo
//   [9M,17M):    cw1   [17M,25M): cw2
//   [25M,41M):   cx (x in bf16)
//   [41M,57M):   buf0: xn1 -> ctx -> xn2
//   [57M,89M):   q(16M),k(16M) -> h1 fp32 (32M)
//   v and FFN z chunks live in d_out.
extern "C" void kernel_launch(void* const* d_in, const int* in_sizes, int n_in,
                              void* d_out, int out_size, void* d_ws, size_t ws_size,
                              hipStream_t stream)
{
    const void* x_raw  = d_in[0];
    const int*  mask   = (const int*)d_in[1];
    const void* wq_raw = d_in[2];
    const void* wk_raw = d_in[3];
    const void* wv_raw = d_in[4];
    const void* wo_raw = d_in[5];
    const void* w1_raw = d_in[6];
    const void* b1_raw = d_in[7];
    const void* w2_raw = d_in[8];
    const void* b2_raw = d_in[9];
    const void* g1_raw = d_in[10];
    const void* be1_raw= d_in[11];
    const void* g2_raw = d_in[12];
    const void* be2_raw= d_in[13];

    char* ws = (char*)d_ws;
    const size_t MB = 1024 * 1024;
    int* flag = (int*)ws;
    unsigned short* cb1  = (unsigned short*)(ws + 1 * 1024);
    unsigned short* cb2  = (unsigned short*)(ws + 16 * 1024);
    unsigned short* cg1  = (unsigned short*)(ws + 32 * 1024);
    unsigned short* cbe1 = (unsigned short*)(ws + 40 * 1024);
    unsigned short* cg2  = (unsigned short*)(ws + 48 * 1024);
    unsigned short* cbe2 = (unsigned short*)(ws + 56 * 1024);
    unsigned short* cwq  = (unsigned short*)(ws + 1 * MB);
    unsigned short* cwk  = (unsigned short*)(ws + 3 * MB);
    unsigned short* cwv  = (unsigned short*)(ws + 5 * MB);
    unsigned short* cwo  = (unsigned short*)(ws + 7 * MB);
    unsigned short* cw1  = (unsigned short*)(ws + 9 * MB);
    unsigned short* cw2  = (unsigned short*)(ws + 17 * MB);
    unsigned short* cx   = (unsigned short*)(ws + 25 * MB);
    unsigned short* buf0 = (unsigned short*)(ws + 41 * MB);  // xn1/ctx/xn2
    unsigned short* q    = (unsigned short*)(ws + 57 * MB);
    unsigned short* k    = (unsigned short*)(ws + 73 * MB);
    float*          h1   = (float*)(ws + 57 * MB);           // over q,k
    unsigned short* v    = (unsigned short*)d_out;
    unsigned short* z    = (unsigned short*)d_out;

    // 1. dtype probe
    dtype_probe<<<1, 256, 0, stream>>>((const unsigned short*)x_raw, flag);

    // 2. convert inputs to bf16 (or copy-through)
    auto cvt = [&](const void* src, unsigned short* dst, int n) {
        const int n8 = n / 8;
        cvt_kernel<<<(n8 + 255) / 256, 256, 0, stream>>>(src, dst, n8, flag);
    };
    cvt(x_raw,  cx,  MTOT * D_);
    cvt(wq_raw, cwq, D_ * D_);
    cvt(wk_raw, cwk, D_ * D_);
    cvt(wv_raw, cwv, D_ * D_);
    cvt(wo_raw, cwo, D_ * D_);
    cvt(w1_raw, cw1, DFF_ * D_);
    cvt(w2_raw, cw2, D_ * DFF_);
    cvt(b1_raw, cb1, DFF_);
    cvt(b2_raw, cb2, D_);
    cvt(g1_raw, cg1, D_);
    cvt(be1_raw, cbe1, D_);
    cvt(g2_raw, cg2, D_);
    cvt(be2_raw, cbe2, D_);

    const dim3 blk(256);
    const dim3 gs(D_ / BN, MTOT / BM);   // (8, 64)

    unsigned short* xn1 = buf0;
    unsigned short* ctx = buf0;
    unsigned short* xn2 = buf0;

    // LN1
    ln_kernel<0><<<MTOT, blk, 0, stream>>>(cx, cg1, cbe1, xn1);
    // QKV
    gemm_bt<0,0,0,0><<<gs, blk, 0, stream>>>(xn1, D_, cwq, D_, nullptr, nullptr, q, MTOT, D_, D_);
    gemm_bt<0,0,0,0><<<gs, blk, 0, stream>>>(xn1, D_, cwk, D_, nullptr, nullptr, k, MTOT, D_, D_);
    gemm_bt<0,0,0,0><<<gs, blk, 0, stream>>>(xn1, D_, cwv, D_, nullptr, nullptr, v, MTOT, D_, D_);
    // attention (ctx overwrites xn1; xn1 dead)
    attn_kernel<<<dim3(S_ / 128, B_ * H_), dim3(128), 0, stream>>>(q, k, v, mask, ctx);
    // out-proj + residual(x) -> h1 fp32 (overwrites q,k)
    gemm_bt<0,0,1,1><<<gs, blk, 0, stream>>>(ctx, D_, cwo, D_, nullptr, cx, h1, MTOT, D_, D_);
    // LN2 (xn2 overwrites ctx; ctx dead)
    ln_kernel<1><<<MTOT, blk, 0, stream>>>(h1, cg2, cbe2, xn2);
    // FFN: 4 chunks of 1024 over DFF; fp32 accumulate into h1; z lives in d_out
    for (int c = 0; c < 4; ++c) {
        const unsigned short* w1c = cw1 + (size_t)c * 1024 * D_;
        const unsigned short* b1c = cb1 + c * 1024;
        const unsigned short* w2c = cw2 + c * 1024;
        gemm_bt<1,1,0,0><<<gs, blk, 0, stream>>>(xn2, D_, w1c, D_, b1c, nullptr, z, MTOT, 1024, D_);
        gemm_bt<0,0,2,1><<<gs, blk, 0, stream>>>(z, 1024, w2c, DFF_, nullptr, h1, h1, MTOT, D_, 1024);
    }
    // final: d_out = h1 + b2 (dtype per flag)
    epi_kernel<<<MTOT, blk, 0, stream>>>(h1, cb2, d_out, flag);
}

// Round 4
// 728.863 us; speedup vs baseline: 3.8603x; 3.8603x over previous
//
#include <hip/hip_runtime.h>
#include <hip/hip_bf16.h>
#include <cstdint>
#include <cstddef>

typedef __attribute__((ext_vector_type(8))) short short8;
typedef __attribute__((ext_vector_type(4))) float floatx4;
typedef __attribute__((ext_vector_type(4))) unsigned short ushort4e;

#define B_   4
#define S_   2048
#define D_   1024
#define H_   16
#define DK_  64
#define DFF_ 4096
#define MTOT (B_ * S_)   // 8192

__device__ __forceinline__ float bf2f(unsigned short u) {
    union { unsigned int i; float f; } v; v.i = ((unsigned int)u) << 16; return v.f;
}
__device__ __forceinline__ unsigned short f2bf(float f) {
    union { float f; unsigned int i; } v; v.f = f;
    unsigned int u = v.i;
    u += 0x7fffu + ((u >> 16) & 1u);   // RNE
    return (unsigned short)(u >> 16);
}
// pack two fp32 -> two bf16 (round-to-nearest, ties-up; inputs finite >=0)
__device__ __forceinline__ unsigned int pkbf(float a, float b) {
    union { float f; unsigned int u; } x, y; x.f = a; y.f = b;
    return ((x.u + 0x8000u) >> 16) | ((y.u + 0x8000u) & 0xffff0000u);
}

// ------------------------------------------------------- dtype detection --
__global__ void dtype_probe(const unsigned short* __restrict__ x, int* flag) {
    __shared__ float red[4];
    const int tid = threadIdx.x;
    float mx = 0.f;
    #pragma unroll
    for (int i = 0; i < 16; i++) {
        float v = fabsf(bf2f(x[tid * 16 + i]));
        if (v != v) v = 1e30f;
        mx = fmaxf(mx, v);
    }
    #pragma unroll
    for (int off = 32; off > 0; off >>= 1) mx = fmaxf(mx, __shfl_down(mx, off));
    if ((tid & 63) == 0) red[tid >> 6] = mx;
    __syncthreads();
    if (tid == 0) {
        float m = fmaxf(fmaxf(red[0], red[1]), fmaxf(red[2], red[3]));
        *flag = (m > 50.f) ? 1 : 0;
    }
}

__global__ void cvt_kernel(const void* __restrict__ src,
                           unsigned short* __restrict__ dst,
                           int n8, const int* __restrict__ flag) {
    const int i = blockIdx.x * 256 + threadIdx.x;
    if (i >= n8) return;
    if (*flag) {
        const floatx4* s = (const floatx4*)src;
        floatx4 a = s[i * 2], b = s[i * 2 + 1];
        short8 o;
        o[0] = (short)f2bf(a[0]); o[1] = (short)f2bf(a[1]);
        o[2] = (short)f2bf(a[2]); o[3] = (short)f2bf(a[3]);
        o[4] = (short)f2bf(b[0]); o[5] = (short)f2bf(b[1]);
        o[6] = (short)f2bf(b[2]); o[7] = (short)f2bf(b[3]);
        ((short8*)dst)[i] = o;
    } else {
        ((short8*)dst)[i] = ((const short8*)src)[i];
    }
}

// ---------------------------------------------------------------- GEMM ----
#define BM 128
#define BN 128
#define BK 64
#define LDK (BK + 8)

template<int RELU, int HAS_BIAS, int RES_MODE, int OUT_F32>
__global__ __launch_bounds__(256)
void gemm_bt(const unsigned short* __restrict__ A, int lda,
             const unsigned short* __restrict__ W, int ldw,
             const unsigned short* __restrict__ bias,
             const void* resid,
             void* out,
             int M, int N, int K)
{
    __shared__ unsigned short As[BM * LDK];
    __shared__ unsigned short Bs[BN * LDK];

    const int tid  = threadIdx.x;
    const int lane = tid & 63;
    const int wave = tid >> 6;
    const int wm = wave >> 1;
    const int wn = wave & 1;
    const int lr = lane & 15;
    const int lq = lane >> 4;

    const int m0 = blockIdx.y * BM;
    const int n0 = blockIdx.x * BN;

    floatx4 acc[4][4];
    #pragma unroll
    for (int i = 0; i < 4; i++)
        #pragma unroll
        for (int j = 0; j < 4; j++)
            acc[i][j] = (floatx4){0.f, 0.f, 0.f, 0.f};

    const int sr = tid >> 3;
    const int sc = (tid & 7) * 8;

    for (int k0 = 0; k0 < K; k0 += BK) {
        #pragma unroll
        for (int p = 0; p < 4; p++) {
            const int row = sr + p * 32;
            short8 av = *(const short8*)(A + (size_t)(m0 + row) * lda + k0 + sc);
            short8 bv = *(const short8*)(W + (size_t)(n0 + row) * ldw + k0 + sc);
            *(short8*)(&As[row * LDK + sc]) = av;
            *(short8*)(&Bs[row * LDK + sc]) = bv;
        }
        __syncthreads();
        #pragma unroll
        for (int kk = 0; kk < BK; kk += 32) {
            short8 af[4], bfr[4];
            #pragma unroll
            for (int i = 0; i < 4; i++) {
                af[i]  = *(const short8*)(&As[(wm * 64 + i * 16 + lr) * LDK + kk + lq * 8]);
                bfr[i] = *(const short8*)(&Bs[(wn * 64 + i * 16 + lr) * LDK + kk + lq * 8]);
            }
            #pragma unroll
            for (int i = 0; i < 4; i++)
                #pragma unroll
                for (int j = 0; j < 4; j++)
                    acc[i][j] = __builtin_amdgcn_mfma_f32_16x16x32_bf16(
                                    af[i], bfr[j], acc[i][j], 0, 0, 0);
        }
        __syncthreads();
    }

    #pragma unroll
    for (int i = 0; i < 4; i++) {
        #pragma unroll
        for (int j = 0; j < 4; j++) {
            const int col = n0 + wn * 64 + j * 16 + lr;
            const float bv = HAS_BIAS ? bf2f(bias[col]) : 0.f;
            #pragma unroll
            for (int r = 0; r < 4; r++) {
                const int row = m0 + wm * 64 + i * 16 + lq * 4 + r;
                float vvv = acc[i][j][r] + bv;
                if (RES_MODE == 1) vvv += bf2f(((const unsigned short*)resid)[(size_t)row * N + col]);
                if (RES_MODE == 2) vvv += ((const float*)resid)[(size_t)row * N + col];
                if (RELU) vvv = fmaxf(vvv, 0.f);
                if (OUT_F32) ((float*)out)[(size_t)row * N + col] = vvv;
                else ((unsigned short*)out)[(size_t)row * N + col] = f2bf(vvv);
            }
        }
    }
}

// ------------------------------------------------------------- LayerNorm --
template<int IN_F32>
__global__ __launch_bounds__(256)
void ln_kernel(const void* __restrict__ Xv,
               const unsigned short* __restrict__ g,
               const unsigned short* __restrict__ be,
               unsigned short* __restrict__ out)
{
    const int row = blockIdx.x;
    const int tid = threadIdx.x;
    float x4[4];
    if (IN_F32) {
        const float* X = (const float*)Xv + (size_t)row * D_ + tid * 4;
        floatx4 t = *(const floatx4*)X;
        x4[0] = t[0]; x4[1] = t[1]; x4[2] = t[2]; x4[3] = t[3];
    } else {
        const unsigned short* X = (const unsigned short*)Xv + (size_t)row * D_ + tid * 4;
        ushort4e u = *(const ushort4e*)X;
        #pragma unroll
        for (int i = 0; i < 4; i++) x4[i] = bf2f(u[i]);
    }
    float s1 = x4[0] + x4[1] + x4[2] + x4[3];
    float s2 = x4[0]*x4[0] + x4[1]*x4[1] + x4[2]*x4[2] + x4[3]*x4[3];
    #pragma unroll
    for (int off = 32; off > 0; off >>= 1) {
        s1 += __shfl_down(s1, off);
        s2 += __shfl_down(s2, off);
    }
    __shared__ float r1[4], r2[4];
    const int wv = tid >> 6;
    if ((tid & 63) == 0) { r1[wv] = s1; r2[wv] = s2; }
    __syncthreads();
    s1 = r1[0] + r1[1] + r1[2] + r1[3];
    s2 = r2[0] + r2[1] + r2[2] + r2[3];
    const float mean = s1 * (1.0f / D_);
    const float var  = (s2 - (float)D_ * mean * mean) * (1.0f / (D_ - 1));
    const float rstd = rsqrtf(var + 1e-9f);

    ushort4e o4;
    #pragma unroll
    for (int i = 0; i < 4; i++) {
        const float gv = bf2f(g[tid * 4 + i]);
        const float bv = bf2f(be[tid * 4 + i]);
        o4[i] = f2bf(gv * (x4[i] - mean) * rstd + bv);
    }
    *(ushort4e*)(out + (size_t)row * D_ + tid * 4) = o4;
}

// -------------------------------------------------- V transpose per head --
// V [token][D] -> Vt [bh][dk][S]  (64 x 2048 per head)
__global__ __launch_bounds__(256)
void vtrans(const unsigned short* __restrict__ V, unsigned short* __restrict__ Vt)
{
    __shared__ unsigned short t[64 * 72];
    const int tid = threadIdx.x;
    const int kt  = blockIdx.x * 64;
    const int bh  = blockIdx.y;
    const int b   = bh >> 4, h = bh & 15;
    const int r   = tid >> 2;
    const int c4  = (tid & 3) * 16;
    const unsigned short* vp = V + (size_t)(b * S_ + kt + r) * D_ + h * DK_ + c4;
    *(short8*)&t[r * 72 + c4]     = *(const short8*)vp;
    *(short8*)&t[r * 72 + c4 + 8] = *(const short8*)(vp + 8);
    __syncthreads();
    short8 o0, o1;
    #pragma unroll
    for (int e = 0; e < 8; e++) {
        o0[e] = (short)t[(c4 + e) * 72 + r];
        o1[e] = (short)t[(c4 + 8 + e) * 72 + r];
    }
    unsigned short* op = Vt + ((size_t)bh * DK_ + r) * S_ + kt + c4;
    *(short8*)op       = o0;
    *(short8*)(op + 8) = o1;
}

// ----------------------------------------------- MFMA flash attention ----
// Block: 256 thr (4 waves), 128 queries; K-tiles of 64 keys.
// Scores computed transposed (A=K, B=Q -> D[key][query]) so P writes pack b64.
// P round-trips LDS (C/D -> A layout); PV: A=P, B=Vt (pre-transposed V).
#define ATK 64
#define KLD 72

__global__ __launch_bounds__(256)
void attn_mfma(const unsigned short* __restrict__ Q,
               const unsigned short* __restrict__ Kg,
               const unsigned short* __restrict__ Vt,
               const int* __restrict__ mask,
               unsigned short* __restrict__ ctx)
{
    __shared__ unsigned short Ks[ATK * KLD];        // [key][dk]
    __shared__ unsigned short Vts[DK_ * KLD];       // [dk][key]
    __shared__ unsigned short Ps[4][32 * KLD];      // per-wave [q 32][key 64]
    __shared__ float maskadd[ATK];
    __shared__ float ared[4][32];

    const int tid  = threadIdx.x;
    const int lane = tid & 63;
    const int w    = tid >> 6;
    const int c    = lane & 15;
    const int qd   = lane >> 4;
    const int bh   = blockIdx.y;
    const int b    = bh >> 4;
    const int h    = bh & 15;
    const int q0   = blockIdx.x * 128 + w * 32;

    // Q fragments (B operand), pre-scaled by 1/8 (exact in bf16)
    short8 qf[2][2];
    #pragma unroll
    for (int jq = 0; jq < 2; jq++)
        #pragma unroll
        for (int kk = 0; kk < 2; kk++) {
            const unsigned short* qp =
                Q + (size_t)(b * S_ + q0 + jq * 16 + c) * D_ + h * DK_ + kk * 32 + qd * 8;
            short8 t = *(const short8*)qp;
            short8 o;
            #pragma unroll
            for (int e = 0; e < 8; e++) {
                float f = bf2f((unsigned short)t[e]) * 0.125f;
                o[e] = (short)f2bf(f);
            }
            qf[jq][kk] = o;
        }

    floatx4 acc_o[2][4];
    #pragma unroll
    for (int iq = 0; iq < 2; iq++)
        #pragma unroll
        for (int jd = 0; jd < 4; jd++)
            acc_o[iq][jd] = (floatx4){0.f, 0.f, 0.f, 0.f};
    float mrun[2] = {-1e30f, -1e30f};
    float lrun[2] = {0.f, 0.f};

    const int srow = tid >> 2;
    const int scol = (tid & 3) * 16;

    for (int kt = 0; kt < S_; kt += ATK) {
        // stage K tile + Vt tile + mask
        {
            const unsigned short* kp = Kg + (size_t)(b * S_ + kt + srow) * D_ + h * DK_ + scol;
            *(short8*)&Ks[srow * KLD + scol]     = *(const short8*)kp;
            *(short8*)&Ks[srow * KLD + scol + 8] = *(const short8*)(kp + 8);
            const unsigned short* vp = Vt + ((size_t)bh * DK_ + srow) * S_ + kt + scol;
            *(short8*)&Vts[srow * KLD + scol]     = *(const short8*)vp;
            *(short8*)&Vts[srow * KLD + scol + 8] = *(const short8*)(vp + 8);
            if (tid < ATK) maskadd[tid] = (mask[b * S_ + kt + tid] == 0) ? -1e9f : 0.f;
        }
        __syncthreads();

        // scores^T: acc_s[i][jq]; key = i*16 + qd*4 + r, query = jq*16 + c
        floatx4 acc_s[4][2];
        #pragma unroll
        for (int i = 0; i < 4; i++)
            #pragma unroll
            for (int jq = 0; jq < 2; jq++)
                acc_s[i][jq] = (floatx4){0.f, 0.f, 0.f, 0.f};
        #pragma unroll
        for (int kk = 0; kk < 2; kk++) {
            short8 kf[4];
            #pragma unroll
            for (int i = 0; i < 4; i++)
                kf[i] = *(const short8*)&Ks[(i * 16 + c) * KLD + kk * 32 + qd * 8];
            #pragma unroll
            for (int i = 0; i < 4; i++)
                #pragma unroll
                for (int jq = 0; jq < 2; jq++)
                    acc_s[i][jq] = __builtin_amdgcn_mfma_f32_16x16x32_bf16(
                                       kf[i], qf[jq][kk], acc_s[i][jq], 0, 0, 0);
        }

        // mask add
        floatx4 madd[4];
        #pragma unroll
        for (int i = 0; i < 4; i++)
            madd[i] = *(const floatx4*)&maskadd[i * 16 + qd * 4];
        #pragma unroll
        for (int i = 0; i < 4; i++)
            #pragma unroll
            for (int jq = 0; jq < 2; jq++)
                #pragma unroll
                for (int r = 0; r < 4; r++)
                    acc_s[i][jq][r] += madd[i][r];

        // online softmax stats per query column
        float alpha[2];
        #pragma unroll
        for (int jq = 0; jq < 2; jq++) {
            float m = -3e38f;
            #pragma unroll
            for (int i = 0; i < 4; i++)
                #pragma unroll
                for (int r = 0; r < 4; r++)
                    m = fmaxf(m, acc_s[i][jq][r]);
            m = fmaxf(m, __shfl_xor(m, 16));
            m = fmaxf(m, __shfl_xor(m, 32));
            const float mnew = fmaxf(mrun[jq], m);
            alpha[jq] = __expf(mrun[jq] - mnew);
            float ps = 0.f;
            #pragma unroll
            for (int i = 0; i < 4; i++)
                #pragma unroll
                for (int r = 0; r < 4; r++) {
                    float p = __expf(acc_s[i][jq][r] - mnew);
                    acc_s[i][jq][r] = p;
                    ps += p;
                }
            ps += __shfl_xor(ps, 16);
            ps += __shfl_xor(ps, 32);
            lrun[jq] = lrun[jq] * alpha[jq] + ps;
            mrun[jq] = mnew;
        }

        // write P (bf16) rows=query, cols=key; 4 consecutive keys -> b64
        #pragma unroll
        for (int jq = 0; jq < 2; jq++)
            #pragma unroll
            for (int i = 0; i < 4; i++) {
                uint2 pk;
                pk.x = pkbf(acc_s[i][jq][0], acc_s[i][jq][1]);
                pk.y = pkbf(acc_s[i][jq][2], acc_s[i][jq][3]);
                *(uint2*)&Ps[w][(jq * 16 + c) * KLD + i * 16 + qd * 4] = pk;
            }

        // rescale O by alpha (redistribute to row layout via per-wave LDS)
        if (lane < 16) { ared[w][c] = alpha[0]; ared[w][16 + c] = alpha[1]; }
        floatx4 av0 = *(const floatx4*)&ared[w][qd * 4];
        floatx4 av1 = *(const floatx4*)&ared[w][16 + qd * 4];
        #pragma unroll
        for (int jd = 0; jd < 4; jd++)
            #pragma unroll
            for (int r = 0; r < 4; r++) {
                acc_o[0][jd][r] *= av0[r];
                acc_o[1][jd][r] *= av1[r];
            }

        // PV: A=P, B=Vt
        #pragma unroll
        for (int kk = 0; kk < 2; kk++) {
            short8 pf[2], vf[4];
            #pragma unroll
            for (int iq = 0; iq < 2; iq++)
                pf[iq] = *(const short8*)&Ps[w][(iq * 16 + c) * KLD + kk * 32 + qd * 8];
            #pragma unroll
            for (int jd = 0; jd < 4; jd++)
                vf[jd] = *(const short8*)&Vts[(jd * 16 + c) * KLD + kk * 32 + qd * 8];
            #pragma unroll
            for (int iq = 0; iq < 2; iq++)
                #pragma unroll
                for (int jd = 0; jd < 4; jd++)
                    acc_o[iq][jd] = __builtin_amdgcn_mfma_f32_16x16x32_bf16(
                                        pf[iq], vf[jd], acc_o[iq][jd], 0, 0, 0);
        }
        __syncthreads();
    }

    // normalize and store
    if (lane < 16) { ared[w][c] = 1.f / lrun[0]; ared[w][16 + c] = 1.f / lrun[1]; }
    floatx4 lv0 = *(const floatx4*)&ared[w][qd * 4];
    floatx4 lv1 = *(const floatx4*)&ared[w][16 + qd * 4];
    #pragma unroll
    for (int iq = 0; iq < 2; iq++)
        #pragma unroll
        for (int jd = 0; jd < 4; jd++)
            #pragma unroll
            for (int r = 0; r < 4; r++) {
                const int row = q0 + iq * 16 + qd * 4 + r;
                const int col = h * DK_ + jd * 16 + c;
                const float inv = (iq == 0) ? lv0[r] : lv1[r];
                ctx[(size_t)(b * S_ + row) * D_ + col] = f2bf(acc_o[iq][jd][r] * inv);
            }
}

// --------------------------------------------------------------- epilogue --
__global__ __launch_bounds__(256)
void epi_kernel(const float* __restrict__ h1,
                const unsigned short* __restrict__ b2,
                void* out, const int* __restrict__ flag)
{
    const int row = blockIdx.x, tid = threadIdx.x;
    floatx4 h = *(const floatx4*)(h1 + (size_t)row * D_ + tid * 4);
    ushort4e bb = *(const ushort4e*)(b2 + tid * 4);
    float r0 = h[0] + bf2f(bb[0]);
    float r1 = h[1] + bf2f(bb[1]);
    float r2 = h[2] + bf2f(bb[2]);
    float r3 = h[3] + bf2f(bb[3]);
    if (*flag) {
        floatx4 o = (floatx4){r0, r1, r2, r3};
        *(floatx4*)((float*)out + (size_t)row * D_ + tid * 4) = o;
    } else {
        ushort4e o;
        o[0] = f2bf(r0); o[1] = f2bf(r1); o[2] = f2bf(r2); o[3] = f2bf(r3);
        *(ushort4e*)((unsigned short*)out + (size_t)row * D_ + tid * 4) = o;
    }
}

// ---------------------------------------------------------------- launch --
// ws (89 MB):
//   [0,4) flag; [1K,64K) small cvt; [1M,25M) weights; [25M,41M) cx
//   [41M,57M) buf0: xn1 -> vt -> xn2
//   [57M,89M) q(16M),k(16M) -> h1 fp32(32M)
//   d_out:    v -> ctx -> z
extern "C" void kernel_launch(void* const* d_in, const int* in_sizes, int n_in,
                              void* d_out, int out_size, void* d_ws, size_t ws_size,
                              hipStream_t stream)
{
    const void* x_raw  = d_in[0];
    const int*  mask   = (const int*)d_in[1];
    const void* wq_raw = d_in[2];
    const void* wk_raw = d_in[3];
    const void* wv_raw = d_in[4];
    const void* wo_raw = d_in[5];
    const void* w1_raw = d_in[6];
    const void* b1_raw = d_in[7];
    const void* w2_raw = d_in[8];
    const void* b2_raw = d_in[9];
    const void* g1_raw = d_in[10];
    const void* be1_raw= d_in[11];
    const void* g2_raw = d_in[12];
    const void* be2_raw= d_in[13];

    char* ws = (char*)d_ws;
    const size_t MB = 1024 * 1024;
    int* flag = (int*)ws;
    unsigned short* cb1  = (unsigned short*)(ws + 1 * 1024);
    unsigned short* cb2  = (unsigned short*)(ws + 16 * 1024);
    unsigned short* cg1  = (unsigned short*)(ws + 32 * 1024);
    unsigned short* cbe1 = (unsigned short*)(ws + 40 * 1024);
    unsigned short* cg2  = (unsigned short*)(ws + 48 * 1024);
    unsigned short* cbe2 = (unsigned short*)(ws + 56 * 1024);
    unsigned short* cwq  = (unsigned short*)(ws + 1 * MB);
    unsigned short* cwk  = (unsigned short*)(ws + 3 * MB);
    unsigned short* cwv  = (unsigned short*)(ws + 5 * MB);
    unsigned short* cwo  = (unsigned short*)(ws + 7 * MB);
    unsigned short* cw1  = (unsigned short*)(ws + 9 * MB);
    unsigned short* cw2  = (unsigned short*)(ws + 17 * MB);
    unsigned short* cx   = (unsigned short*)(ws + 25 * MB);
    unsigned short* buf0 = (unsigned short*)(ws + 41 * MB);
    unsigned short* q    = (unsigned short*)(ws + 57 * MB);
    unsigned short* k    = (unsigned short*)(ws + 73 * MB);
    float*          h1   = (float*)(ws + 57 * MB);
    unsigned short* v    = (unsigned short*)d_out;
    unsigned short* ctx  = (unsigned short*)d_out;
    unsigned short* z    = (unsigned short*)d_out;
    unsigned short* xn1  = buf0;
    unsigned short* vt   = buf0;
    unsigned short* xn2  = buf0;

    dtype_probe<<<1, 256, 0, stream>>>((const unsigned short*)x_raw, flag);

    auto cvt = [&](const void* src, unsigned short* dst, int n) {
        const int n8 = n / 8;
        cvt_kernel<<<(n8 + 255) / 256, 256, 0, stream>>>(src, dst, n8, flag);
    };
    cvt(x_raw,  cx,  MTOT * D_);
    cvt(wq_raw, cwq, D_ * D_);
    cvt(wk_raw, cwk, D_ * D_);
    cvt(wv_raw, cwv, D_ * D_);
    cvt(wo_raw, cwo, D_ * D_);
    cvt(w1_raw, cw1, DFF_ * D_);
    cvt(w2_raw, cw2, D_ * DFF_);
    cvt(b1_raw, cb1, DFF_);
    cvt(b2_raw, cb2, D_);
    cvt(g1_raw, cg1, D_);
    cvt(be1_raw, cbe1, D_);
    cvt(g2_raw, cg2, D_);
    cvt(be2_raw, cbe2, D_);

    const dim3 blk(256);
    const dim3 gs(D_ / BN, MTOT / BM);

    // LN1
    ln_kernel<0><<<MTOT, blk, 0, stream>>>(cx, cg1, cbe1, xn1);
    // QKV
    gemm_bt<0,0,0,0><<<gs, blk, 0, stream>>>(xn1, D_, cwq, D_, nullptr, nullptr, q, MTOT, D_, D_);
    gemm_bt<0,0,0,0><<<gs, blk, 0, stream>>>(xn1, D_, cwk, D_, nullptr, nullptr, k, MTOT, D_, D_);
    gemm_bt<0,0,0,0><<<gs, blk, 0, stream>>>(xn1, D_, cwv, D_, nullptr, nullptr, v, MTOT, D_, D_);
    // V transpose per head (xn1 dead -> vt)
    vtrans<<<dim3(S_ / 64, B_ * H_), blk, 0, stream>>>(v, vt);
    // attention (v dead -> ctx in d_out)
    attn_mfma<<<dim3(S_ / 128, B_ * H_), blk, 0, stream>>>(q, k, vt, mask, ctx);
    // out-proj + residual(x) -> h1 fp32 (q,k dead)
    gemm_bt<0,0,1,1><<<gs, blk, 0, stream>>>(ctx, D_, cwo, D_, nullptr, cx, h1, MTOT, D_, D_);
    // LN2 (vt dead -> xn2)
    ln_kernel<1><<<MTOT, blk, 0, stream>>>(h1, cg2, cbe2, xn2);
    // FFN: 4 chunks of 1024; fp32 accumulate into h1; z in d_out (ctx dead)
    for (int c = 0; c < 4; ++c) {
        const unsigned short* w1c = cw1 + (size_t)c * 1024 * D_;
        const unsigned short* b1c = cb1 + c * 1024;
        const unsigned short* w2c = cw2 + c * 1024;
        gemm_bt<1,1,0,0><<<gs, blk, 0, stream>>>(xn2, D_, w1c, D_, b1c, nullptr, z, MTOT, 1024, D_);
        gemm_bt<0,0,2,1><<<gs, blk, 0, stream>>>(z, 1024, w2c, DFF_, nullptr, h1, h1, MTOT, D_, 1024);
    }
    epi_kernel<<<MTOT, blk, 0, stream>>>(h1, cb2, d_out, flag);
}